// Round 15
// baseline (994.853 us; speedup 1.0000x reference)
//
#include <hip/hip_runtime.h>
#include <hip/hip_cooperative_groups.h>

namespace cg = cooperative_groups;

// Problem sizes (fixed): B=128, Tm1=64, M=P=512
typedef _Float16 v8h __attribute__((ext_vector_type(8)));
typedef _Float16 h2v __attribute__((ext_vector_type(2)));
typedef float v4f __attribute__((ext_vector_type(4)));

#define SCOPE_AGENT __HIP_MEMORY_SCOPE_AGENT

// Sentinels (impossible as real data: NaN encodings)
#define SA32 0x7E007E00u                     // two f16 NaNs (Ab words)
#define SA64 0x7E007E007E007E00ull
#define SP32 0x7FC0DEADu                     // f32 NaN (partS words)
#define SP64 0x7FC0DEAD7FC0DEADull

static __device__ __forceinline__ uint32_t ald32(const uint32_t* p) {
    return __hip_atomic_load(p, __ATOMIC_RELAXED, SCOPE_AGENT);
}
static __device__ __forceinline__ uint64_t ald64(const uint64_t* p) {
    return __hip_atomic_load(p, __ATOMIC_RELAXED, SCOPE_AGENT);
}
static __device__ __forceinline__ void ast32(uint32_t* p, uint32_t v) {
    __hip_atomic_store(p, v, __ATOMIC_RELAXED, SCOPE_AGENT);
}
static __device__ __forceinline__ void ast64(uint64_t* p, uint64_t v) {
    __hip_atomic_store(p, v, __ATOMIC_RELAXED, SCOPE_AGENT);
}
static __device__ __forceinline__ v8h mkv8(uint64_t lo, uint64_t hi) {
    union { uint64_t q[2]; v8h h; } u; u.q[0] = lo; u.q[1] = hi; return u.h;
}
static __device__ __forceinline__ uint32_t packh(float a, float b) {
    uint16_t ua = __builtin_bit_cast(uint16_t, (_Float16)a);
    uint16_t ub = __builtin_bit_cast(uint16_t, (_Float16)b);
    return (uint32_t)ua | ((uint32_t)ub << 16);
}
static __device__ __forceinline__ float fast_rcp(float x) {
    float y;
    asm("v_rcp_f32 %0, %1" : "=v"(y) : "v"(x));
    return y;
}
static __device__ __forceinline__ float fast_tanh(float x) {
    float e = __expf(2.0f * x);
    return 1.0f - 2.0f * fast_rcp(e + 1.0f);
}
static __device__ __forceinline__ float fast_sigmoid(float x) {
    return fast_rcp(1.0f + __expf(-x));
}
static __device__ __forceinline__ v8h cvt8(const float* p) {
    float4 a = *(const float4*)p;
    float4 b = *(const float4*)(p + 4);
    v8h h;
    h[0] = (_Float16)a.x; h[1] = (_Float16)a.y; h[2] = (_Float16)a.z; h[3] = (_Float16)a.w;
    h[4] = (_Float16)b.x; h[5] = (_Float16)b.y; h[6] = (_Float16)b.z; h[7] = (_Float16)b.w;
    return h;
}

// fWB flag lines (glin only — off critical path):
// fWB [g][p][w] : line FWB + (g*128 + p*16 + w)
#define FWB_OFF 65536

static __device__ __forceinline__ void wait_lines(const uint32_t* base, int n, uint32_t target) {
    if ((int)threadIdx.x < n) {
        const uint32_t* p = base + threadIdx.x * 32;
        while (ald32(p) < target) __builtin_amdgcn_s_sleep(1);
    }
    __syncthreads();
    asm volatile("" ::: "memory");
}
static __device__ __forceinline__ void publish_lines(uint32_t* base, int n, int stride_u32, uint32_t v) {
    asm volatile("s_waitcnt vmcnt(0)" ::: "memory");
    __syncthreads();
    if ((int)threadIdx.x < n) ast32(base + threadIdx.x * stride_u32, v);
}

// Grid: 256 blocks x 512 threads, cooperative.
// 8 groups, group r = batches [16r,+16):
//   workers bid 0..127 (r=bid>>4, w=bid&15): poll Ab[t&1] data (sentinel),
//     s-slice MFMA + tanh score partials -> partS[t&1] (data-as-flag),
//     glin in softmax shadow (fWB flag).
//   bid 128..191: prologue only.
//   pairs bid 192..255 (p=bid-192): poll partS[t&1] data, re-sentinel consumed
//     regions, softmax/context/ytilde/gates, write Ab[(t+1)&1] after vmcnt drain.
__global__ __launch_bounds__(512, 2) void fused_decoder(
    const float* __restrict__ Xe, const float* __restrict__ ypr,
    const float* __restrict__ Wa1, const float* __restrict__ ba1,
    const float* __restrict__ Wa2, const float* __restrict__ ba2,
    const float* __restrict__ Wih, const float* __restrict__ Whh,
    const float* __restrict__ bih, const float* __restrict__ bhh,
    const float* __restrict__ Wfc, const float* __restrict__ bfc,
    const float* __restrict__ Wfin, const float* __restrict__ bfin,
    float* __restrict__ out,
    uint32_t* __restrict__ ctrs,          // flag lines (fWB region used)
    _Float16* __restrict__ Ab,            // [2][128][1024] f16 — double-buffered
    float* __restrict__ glin,             // [128][2048] f32 (+biases)
    float* __restrict__ partS,            // [2][64 p][2 b][64 t][16 w] f32 — dbuf
    _Float16* __restrict__ hx,            // [8192][512] f16
    _Float16* __restrict__ Wa1a,          // [512][1024] f16
    _Float16* __restrict__ Whh16)         // [2048][512] f16
{
    cg::grid_group gg = cg::this_grid();
    const int bid = blockIdx.x;
    const int tid = threadIdx.x;
    const int wave = tid >> 6, lane = tid & 63;
    const int l15 = lane & 15, kq = lane >> 4;
    const int gt = bid * 512 + tid;

    __shared__ __align__(16) char arena[143888];

    // ===== sync #1: flush poison-dirty ws lines from all L2s =====
    gg.sync();

    // ===== prologue: NORMAL stores, 128B-line-owned per thread =====
    if (gt < 8192) {                       // Wa1a [512][1024] <- Wa1[:,0:1024)
        int row = gt >> 4, seg = gt & 15;
        const float* src = Wa1 + (size_t)row * 1536 + seg * 64;
        _Float16* dp = Wa1a + (size_t)row * 1024 + seg * 64;
#pragma unroll
        for (int i = 0; i < 8; ++i) *(v8h*)(dp + i * 8) = cvt8(src + i * 8);
    } else if (gt < 24576) {               // Whh16 [2048][512]
        int u = gt - 8192;
        int row = u >> 3, seg = u & 7;
        const float* src = Whh + (size_t)row * 512 + seg * 64;
        _Float16* dp = Whh16 + (size_t)row * 512 + seg * 64;
#pragma unroll
        for (int i = 0; i < 8; ++i) *(v8h*)(dp + i * 8) = cvt8(src + i * 8);
    } else if (gt < 26624) {               // Ab buf0: zeros (initial d=c=0)
        uint64_t* p = (uint64_t*)Ab + (size_t)(gt - 24576) * 16;
#pragma unroll
        for (int i = 0; i < 16; ++i) p[i] = 0ull;
    } else if (gt < 28672) {               // Ab buf1: sentinel
        uint64_t* p = (uint64_t*)Ab + 32768 + (size_t)(gt - 26624) * 16;
#pragma unroll
        for (int i = 0; i < 16; ++i) p[i] = SA64;
    } else if (gt < 36864) {               // partS both buffers: sentinel (1 MB)
        uint64_t* p = (uint64_t*)partS + (size_t)(gt - 28672) * 16;
#pragma unroll
        for (int i = 0; i < 16; ++i) p[i] = SP64;
    } else if (gt < 69632) {               // fWB flag region zero (32768 u32)
        ctrs[FWB_OFF + (gt - 36864)] = 0u;
    }
    // hx = f16(Xe @ Wa1[:,1024:]^T + ba1) — all 256 blocks
    {
        const int wg = bid * 8 + wave;                 // 0..2047
        const int mt = wg >> 2;
        const int nq = wg & 3;
        const float* Abase = Xe + (size_t)(mt * 16 + l15) * 512 + kq * 8;
        v8h afr[16];
#pragma unroll
        for (int ks = 0; ks < 16; ++ks) afr[ks] = cvt8(Abase + ks * 32);
#pragma unroll
        for (int i = 0; i < 8; ++i) {
            const int nt = nq * 8 + i;
            const float* Bbase = Wa1 + (size_t)(nt * 16 + l15) * 1536 + 1024 + kq * 8;
            v4f acc = {};
#pragma unroll 4
            for (int ks = 0; ks < 16; ++ks)
                acc = __builtin_amdgcn_mfma_f32_16x16x32_f16(afr[ks], cvt8(Bbase + ks * 32), acc, 0, 0, 0);
            const float bav = ba1[nt * 16 + l15];
            _Float16* hrow = hx + (size_t)(mt * 16 + kq * 4) * 512 + nt * 16 + l15;
#pragma unroll
            for (int r = 0; r < 4; ++r) hrow[(size_t)r * 512] = (_Float16)(acc[r] + bav);
        }
    }
    // ===== sync #2: publish prologue; all L2s clean =====
    gg.sync();

    if (bid >= 128 && bid < 192) return;

    // =========================== main recurrence =============================
    if (bid < 128) {
        // ------------ worker: s-slice [32w,+32) + glin [128w,+128) ------------
        const int r = bid >> 4, w = bid & 15;
        const int g16 = r * 16;
        uint32_t* fWBbase = ctrs + FWB_OFF + (size_t)(r * 128 + w) * 32;   // stride 16*32
        _Float16* hxL = (_Float16*)arena;               // 64 KB, [c][cmb][8] chunked
        float* red = (float*)(arena + 65536);           // 64 KB (s / glin reduce)
        float* s_tile = (float*)(arena + 131072);       // 2 KB
        float* w2l = (float*)(arena + 133120);          // 128 B

        for (int cmb = tid; cmb < 1024; cmb += 512) {
            const int b = cmb >> 6, tt = cmb & 63;
            const _Float16* src = hx + ((size_t)(g16 + b) * 64 + tt) * 512 + w * 32;
#pragma unroll
            for (int c = 0; c < 4; ++c)
                *(v8h*)(hxL + ((size_t)(c * 1024 + cmb) << 3)) = *(const v8h*)(src + c * 8);
        }
        if (tid < 32) w2l[tid] = Wa2[w * 32 + tid];
        __syncthreads();

        const uint64_t* Abq = (const uint64_t*)Ab;
        v8h B0r[4], B1r[4];
#pragma unroll
        for (int k2 = 0; k2 < 4; ++k2) {
            const int kk = wave * 4 + k2;
            B0r[k2] = *(const v8h*)(Wa1a + (size_t)(w * 32 + l15) * 1024 + kk * 32 + kq * 8);
            B1r[k2] = *(const v8h*)(Wa1a + (size_t)(w * 32 + 16 + l15) * 1024 + kk * 32 + kq * 8);
        }
        v8h Bgr[8][2];
#pragma unroll
        for (int nt = 0; nt < 8; ++nt)
#pragma unroll
            for (int i = 0; i < 2; ++i)
                Bgr[nt][i] = *(const v8h*)(Whh16 + (size_t)(w * 128 + nt * 16 + l15) * 512
                                           + (wave * 2 + i) * 32 + kq * 8);
        float bbv[4];
#pragma unroll
        for (int j = 0; j < 4; ++j) {
            const int gcol = w * 128 + ((tid + j * 512) & 127);
            bbv[j] = bih[gcol] + bhh[gcol];
        }
        uint32_t* partOut = (uint32_t*)partS;

        for (int t = 0; t < 64; ++t) {
            // ---- poll Ab[t&1] data directly (sentinel-based, no flag) ----
            const uint64_t* ab = Abq + (size_t)(t & 1) * 32768
                               + (size_t)(g16 + l15) * 256 + kq * 2;
            uint64_t ls[8], lg[4];
            for (;;) {
                bool ok = true;
#pragma unroll
                for (int k2 = 0; k2 < 4; ++k2) {
                    ls[2 * k2]     = ald64(ab + (wave * 4 + k2) * 8);
                    ls[2 * k2 + 1] = ald64(ab + (wave * 4 + k2) * 8 + 1);
                }
#pragma unroll
                for (int i = 0; i < 2; ++i) {
                    lg[2 * i]     = ald64(ab + (wave * 2 + i) * 8);
                    lg[2 * i + 1] = ald64(ab + (wave * 2 + i) * 8 + 1);
                }
#pragma unroll
                for (int j = 0; j < 8; ++j)
                    ok = ok && ((uint32_t)ls[j] != SA32) && ((uint32_t)(ls[j] >> 32) != SA32);
#pragma unroll
                for (int j = 0; j < 4; ++j)
                    ok = ok && ((uint32_t)lg[j] != SA32) && ((uint32_t)(lg[j] >> 32) != SA32);
                if (ok) break;
                __builtin_amdgcn_s_sleep(0);
            }
            asm volatile("" ::: "memory");

            // ---- s-slice MFMA: wave owns ksegs [4w,+4), B in registers ----
            v4f a0 = {}, a1 = {};
#pragma unroll
            for (int k2 = 0; k2 < 4; ++k2) {
                const v8h af = mkv8(ls[2 * k2], ls[2 * k2 + 1]);
                a0 = __builtin_amdgcn_mfma_f32_16x16x32_f16(af, B0r[k2], a0, 0, 0, 0);
                a1 = __builtin_amdgcn_mfma_f32_16x16x32_f16(af, B1r[k2], a1, 0, 0, 0);
            }
#pragma unroll
            for (int rr = 0; rr < 4; ++rr) {
                red[wave * 512 + (kq * 4 + rr) * 32 + l15] = a0[rr];
                red[wave * 512 + (kq * 4 + rr) * 32 + 16 + l15] = a1[rr];
            }
            __syncthreads();
            {
                float ssum = 0.0f;
#pragma unroll
                for (int wv = 0; wv < 8; ++wv) ssum += red[wv * 512 + tid];
                s_tile[tid] = ssum;
            }
            __syncthreads();

            // ---- tanh score partials -> partS[t&1] (data-as-flag stores) ----
#pragma unroll
            for (int cc = 0; cc < 2; ++cc) {
                const int cmb = tid + cc * 512;
                const int b = cmb >> 6, tt = cmb & 63;
                const _Float16* hb = hxL + ((size_t)cmb << 3);
                float acc = 0.0f;
#pragma unroll
                for (int q = 0; q < 4; ++q) {
                    const v8h hv = *(const v8h*)(hb + ((size_t)q << 13));
#pragma unroll
                    for (int j = 0; j < 8; ++j)
                        acc += w2l[q * 8 + j] *
                               fast_tanh(s_tile[b * 32 + q * 8 + j] + (float)hv[j]);
                }
                const int pg = r * 8 + (b >> 1);
                ast32(partOut + (size_t)(t & 1) * 131072
                      + (((size_t)pg * 2 + (b & 1)) * 64 + tt) * 16 + w,
                      __builtin_bit_cast(uint32_t, acc));
            }

            // ---- glin (softmax shadow): wave owns d-ksegs [2w,+2) ----
#pragma unroll
            for (int nt = 0; nt < 8; ++nt) {
                v4f ag = {};
#pragma unroll
                for (int i = 0; i < 2; ++i)
                    ag = __builtin_amdgcn_mfma_f32_16x16x32_f16(
                        mkv8(lg[2 * i], lg[2 * i + 1]), Bgr[nt][i], ag, 0, 0, 0);
#pragma unroll
                for (int rr = 0; rr < 4; ++rr)
                    red[wave * 2048 + (kq * 4 + rr) * 128 + nt * 16 + l15] = ag[rr];
            }
            __syncthreads();
#pragma unroll
            for (int j = 0; j < 4; ++j) {
                const int o = tid + j * 512;           // row*128+col
                float gsum = 0.0f;
#pragma unroll
                for (int wv = 0; wv < 8; ++wv) gsum += red[wv * 2048 + o];
                ast32((uint32_t*)glin + (size_t)(g16 + (o >> 7)) * 2048 + w * 128 + (o & 127),
                      __builtin_bit_cast(uint32_t, gsum + bbv[j]));
            }
            publish_lines(fWBbase, 8, 16 * 32, (uint32_t)(t + 1));
        }
    } else {
        // ------------------ pair block ------------------
        const int p = bid - 192, b0 = 2 * p, r = p >> 3, pl = p & 7;
        const uint32_t* fWBbase = ctrs + FWB_OFF + (size_t)(r * 128 + pl * 16) * 32;  // poll 16
        _Float16* XeL = (_Float16*)arena;               // 128 KB
        float* sc = (float*)(arena + 131072);
        float* dstL = (float*)(arena + 131584);         // [2][512] (t=63 only)
        float* ctxl = (float*)(arena + 135680);         // [2][512]
        float* ytl = (float*)(arena + 139776);
        float* red0 = (float*)(arena + 139784);

        {
            const float* xsrc = Xe + (size_t)b0 * 64 * 512;
#pragma unroll
            for (int i = 0; i < 16; ++i) {
                const int u = tid + i * 512;
                *(v8h*)(XeL + (size_t)u * 8) = cvt8(xsrc + (size_t)u * 8);
            }
        }
        const float wih_i = Wih[tid], wih_f = Wih[512 + tid],
                    wih_g = Wih[1024 + tid], wih_o = Wih[1536 + tid];
        float creg[2] = {0.0f, 0.0f}, dreg[2] = {0.0f, 0.0f};
        uint32_t* Abu = (uint32_t*)Ab;
        __syncthreads();

        const int cmbG = tid >> 2, wq = tid & 3;
        const int blvG = cmbG >> 6, ttG = cmbG & 63;

        for (int t = 0; t < 64; ++t) {
            // ---- gather: poll partS[t&1] data directly (2 x ald64 / thread) ----
            uint64_t* gb = (uint64_t*)partS + (size_t)(t & 1) * 65536
                         + (((size_t)p * 2 + blvG) * 64 + ttG) * 8 + wq * 2;
            uint64_t q0, q1;
            for (;;) {
                q0 = ald64(gb);
                q1 = ald64(gb + 1);
                bool ok = ((uint32_t)q0 != SP32) && ((uint32_t)(q0 >> 32) != SP32)
                       && ((uint32_t)q1 != SP32) && ((uint32_t)(q1 >> 32) != SP32);
                if (ok) break;
                __builtin_amdgcn_s_sleep(0);
            }
            asm volatile("" ::: "memory");
            float acc = __builtin_bit_cast(float, (uint32_t)q0)
                      + __builtin_bit_cast(float, (uint32_t)(q0 >> 32))
                      + __builtin_bit_cast(float, (uint32_t)q1)
                      + __builtin_bit_cast(float, (uint32_t)(q1 >> 32));
            // re-sentinel consumed words + this pair's Ab[t&1] rows
            ast64(gb, SP64);
            ast64(gb + 1, SP64);
            ast32(Abu + (size_t)(t & 1) * 65536 + (size_t)b0 * 512 + tid, SA32);
            ast32(Abu + (size_t)(t & 1) * 65536 + (size_t)(b0 + 1) * 512 + tid, SA32);
            acc += __shfl_xor(acc, 1, 64);
            acc += __shfl_xor(acc, 2, 64);
            if (wq == 0) sc[cmbG] = acc;
            __syncthreads();

            // ---- joint softmax over the pair's 128 scores ----
            if (tid < 64) {
                float m2 = fmaxf(sc[tid], sc[tid + 64]);
#pragma unroll
                for (int off = 32; off; off >>= 1) m2 = fmaxf(m2, __shfl_xor(m2, off, 64));
                float e0v = __expf(sc[tid] - m2);
                float e1v = __expf(sc[tid + 64] - m2);
                sc[tid] = e0v; sc[tid + 64] = e1v;
                float ssum = e0v + e1v;
#pragma unroll
                for (int off = 32; off; off >>= 1) ssum += __shfl_xor(ssum, off, 64);
                if (tid == 0) red0[0] = 1.0f / ssum;
            }
            __syncthreads();
            const float inv = red0[0];

            // ---- glin ready; issue gate loads, drain under context+ytilde ----
            wait_lines(fWBbase, 16, (uint32_t)(t + 1));
            uint32_t gv[2][4];
#pragma unroll
            for (int blv = 0; blv < 2; ++blv) {
                const uint32_t* gb2 = (const uint32_t*)glin + (size_t)(b0 + blv) * 2048 + tid;
                gv[blv][0] = ald32(gb2);
                gv[blv][1] = ald32(gb2 + 512);
                gv[blv][2] = ald32(gb2 + 1024);
                gv[blv][3] = ald32(gb2 + 1536);
            }

            // ---- context from XeL (LDS) ----
            {
                const int blv = tid >> 8, m2 = (tid & 255) * 2;
                const _Float16* xb = XeL + (size_t)blv * 64 * 512 + m2;
                float a0 = 0.0f, a1 = 0.0f;
#pragma unroll 8
                for (int tt = 0; tt < 64; ++tt) {
                    const h2v xv = *(const h2v*)(xb + (size_t)tt * 512);
                    const float bta = sc[blv * 64 + tt];
                    a0 += bta * (float)xv[0];
                    a1 += bta * (float)xv[1];
                }
                ctxl[blv * 512 + m2] = a0 * inv;
                ctxl[blv * 512 + m2 + 1] = a1 * inv;
            }
            __syncthreads();

            // ---- y_tilde ----
            if (tid < 128) {
                const int blv = tid >> 6, l2 = tid & 63;
                float acc2 = 0.0f;
#pragma unroll
                for (int j = 0; j < 8; ++j) acc2 += ctxl[blv * 512 + l2 * 8 + j] * Wfc[l2 * 8 + j];
#pragma unroll
                for (int off = 32; off; off >>= 1) acc2 += __shfl_xor(acc2, off, 64);
                if (l2 == 0)
                    ytl[blv] = acc2 + Wfc[512] * ypr[(size_t)(b0 + blv) * 64 + t] + bfc[0];
            }
            // drain sentinel stores (and everything else) before Ab values go out
            asm volatile("s_waitcnt vmcnt(0)" ::: "memory");
            __syncthreads();

            // ---- gates + LSTM update (reg state); Ab[(t+1)&1] data-as-flag ----
            const size_t abOff = (size_t)((t + 1) & 1) * 65536;
#pragma unroll
            for (int blv = 0; blv < 2; ++blv) {
                const float yt = ytl[blv];
                float ii = __builtin_bit_cast(float, gv[blv][0]) + yt * wih_i;
                float ff = __builtin_bit_cast(float, gv[blv][1]) + yt * wih_f;
                float ggv = __builtin_bit_cast(float, gv[blv][2]) + yt * wih_g;
                float oo = __builtin_bit_cast(float, gv[blv][3]) + yt * wih_o;
                float cn = fast_sigmoid(ff) * creg[blv] + fast_sigmoid(ii) * fast_tanh(ggv);
                float dn = fast_sigmoid(oo) * fast_tanh(cn);
                creg[blv] = cn;
                dreg[blv] = dn;
                float dp = __shfl_xor(dn, 1, 64);
                float cp = __shfl_xor(cn, 1, 64);
                if (!(tid & 1)) {
                    ast32(Abu + abOff + (size_t)(b0 + blv) * 512 + (tid >> 1), packh(dn, dp));
                    ast32(Abu + abOff + (size_t)(b0 + blv) * 512 + 256 + (tid >> 1), packh(cn, cp));
                }
            }
            if (t == 63) {
                dstL[tid] = dreg[0];
                dstL[512 + tid] = dreg[1];
                __syncthreads();
                if (tid < 128) {
                    const int blv = tid >> 6, l2 = tid & 63;
                    float acc2 = 0.0f;
#pragma unroll
                    for (int j = 0; j < 8; ++j) {
                        const int e = l2 * 8 + j;
                        acc2 += dstL[blv * 512 + e] * Wfin[e] + ctxl[blv * 512 + e] * Wfin[512 + e];
                    }
#pragma unroll
                    for (int off = 32; off; off >>= 1) acc2 += __shfl_xor(acc2, off, 64);
                    if (l2 == 0) out[b0 + blv] = acc2 + bfin[0];
                }
            }
        }
    }
}

extern "C" void kernel_launch(void* const* d_in, const int* in_sizes, int n_in,
                              void* d_out, int out_size, void* d_ws, size_t ws_size,
                              hipStream_t stream)
{
    const float* Xe   = (const float*)d_in[0];
    const float* ypr  = (const float*)d_in[1];
    const float* Wa1  = (const float*)d_in[2];
    const float* ba1  = (const float*)d_in[3];
    const float* Wa2  = (const float*)d_in[4];
    const float* ba2  = (const float*)d_in[5];
    const float* Wih  = (const float*)d_in[6];
    const float* Whh  = (const float*)d_in[7];
    const float* bih  = (const float*)d_in[8];
    const float* bhh  = (const float*)d_in[9];
    const float* Wfc  = (const float*)d_in[10];
    const float* bfc  = (const float*)d_in[11];
    const float* Wfin = (const float*)d_in[12];
    const float* bfin = (const float*)d_in[13];
    float* out = (float*)d_out;

    char* w = (char*)d_ws;
    uint32_t* ctrs  = (uint32_t*)w;                 w += 393216;                        // 384 KB
    _Float16* Ab    = (_Float16*)w;                 w += (size_t)2 * 128 * 1024 * 2;    // 512 KB
    float*    glin  = (float*)w;                    w += (size_t)128 * 2048 * 4;        // 1 MB
    float*    partS = (float*)w;                    w += (size_t)2 * 64 * 2 * 64 * 16 * 4; // 1 MB
    _Float16* hx    = (_Float16*)w;                 w += (size_t)8192 * 512 * 2;        // 8 MB
    _Float16* Wa1a  = (_Float16*)w;                 w += (size_t)512 * 1024 * 2;        // 1 MB
    _Float16* Whh16 = (_Float16*)w;                 w += (size_t)2048 * 512 * 2;        // 2 MB

    void* args[] = {
        (void*)&Xe, (void*)&ypr, (void*)&Wa1, (void*)&ba1, (void*)&Wa2, (void*)&ba2,
        (void*)&Wih, (void*)&Whh, (void*)&bih, (void*)&bhh, (void*)&Wfc, (void*)&bfc,
        (void*)&Wfin, (void*)&bfin, (void*)&out,
        (void*)&ctrs, (void*)&Ab, (void*)&glin, (void*)&partS, (void*)&hx,
        (void*)&Wa1a, (void*)&Whh16
    };
    hipLaunchCooperativeKernel((const void*)fused_decoder, dim3(256), dim3(512),
                               args, 0, stream);
}

// Round 16
// 855.546 us; speedup vs baseline: 1.1628x; 1.1628x over previous
//
#include <hip/hip_runtime.h>
#include <hip/hip_cooperative_groups.h>

namespace cg = cooperative_groups;

// Problem sizes (fixed): B=128, Tm1=64, M=P=512
typedef _Float16 v8h __attribute__((ext_vector_type(8)));
typedef _Float16 h2v __attribute__((ext_vector_type(2)));
typedef float v4f __attribute__((ext_vector_type(4)));

#define SCOPE_AGENT __HIP_MEMORY_SCOPE_AGENT

static __device__ __forceinline__ uint32_t ald32(const uint32_t* p) {
    return __hip_atomic_load(p, __ATOMIC_RELAXED, SCOPE_AGENT);
}
static __device__ __forceinline__ uint64_t ald64(const uint64_t* p) {
    return __hip_atomic_load(p, __ATOMIC_RELAXED, SCOPE_AGENT);
}
static __device__ __forceinline__ void ast32(uint32_t* p, uint32_t v) {
    __hip_atomic_store(p, v, __ATOMIC_RELAXED, SCOPE_AGENT);
}
static __device__ __forceinline__ v8h mkv8(uint64_t lo, uint64_t hi) {
    union { uint64_t q[2]; v8h h; } u; u.q[0] = lo; u.q[1] = hi; return u.h;
}
static __device__ __forceinline__ uint32_t packh(float a, float b) {
    uint16_t ua = __builtin_bit_cast(uint16_t, (_Float16)a);
    uint16_t ub = __builtin_bit_cast(uint16_t, (_Float16)b);
    return (uint32_t)ua | ((uint32_t)ub << 16);
}
static __device__ __forceinline__ float fast_rcp(float x) {
    float y;
    asm("v_rcp_f32 %0, %1" : "=v"(y) : "v"(x));
    return y;
}
static __device__ __forceinline__ float fast_tanh(float x) {
    float e = __expf(2.0f * x);
    return 1.0f - 2.0f * fast_rcp(e + 1.0f);
}
static __device__ __forceinline__ float fast_sigmoid(float x) {
    return fast_rcp(1.0f + __expf(-x));
}
static __device__ __forceinline__ v8h cvt8(const float* p) {
    float4 a = *(const float4*)p;
    float4 b = *(const float4*)(p + 4);
    v8h h;
    h[0] = (_Float16)a.x; h[1] = (_Float16)a.y; h[2] = (_Float16)a.z; h[3] = (_Float16)a.w;
    h[4] = (_Float16)b.x; h[5] = (_Float16)b.y; h[6] = (_Float16)b.z; h[7] = (_Float16)b.w;
    return h;
}

// ---- private flag lines: ONE writer block, ONE reader block per 128B line ----
// fP  [g][w][p] : line (g*128 + w*8 + p)            — pair p writes, worker w reads
// fWA [g][p][w] : line FWA + (g*128 + p*16 + w)     — worker w writes, pair p reads
// fWB [g][p][w] : line FWB + (g*128 + p*16 + w)
#define FWA_OFF 32768
#define FWB_OFF 65536

static __device__ __forceinline__ void wait_lines(const uint32_t* base, int n, uint32_t target) {
    if ((int)threadIdx.x < n) {
        const uint32_t* p = base + threadIdx.x * 32;
        while (ald32(p) < target) __builtin_amdgcn_s_sleep(1);
    }
    __syncthreads();
    asm volatile("" ::: "memory");
}
static __device__ __forceinline__ void publish_lines(uint32_t* base, int n, int stride_u32, uint32_t v) {
    asm volatile("s_waitcnt vmcnt(0)" ::: "memory");   // agent stores reached LLC
    __syncthreads();
    if ((int)threadIdx.x < n) ast32(base + threadIdx.x * stride_u32, v);
}

// Grid: 256 blocks x 512 threads, cooperative.
// 8 groups, group r = batches [16r,+16):
//   workers bid 0..127 (r=bid>>4, w=bid&15): s-slice cols[32w,+32) K-split-8 +
//     tanh score partials, then glin cols[128w,+128) K-split-8 (softmax shadow).
//   bid 128..191: prologue only.
//   pairs bid 192..255 (p=bid-192): softmax -> ytilde (via precomputed XW) ->
//     gates -> Ab publish. Context only at t=63 (feeds final output only).
__global__ __launch_bounds__(512, 2) void fused_decoder(
    const float* __restrict__ Xe, const float* __restrict__ ypr,
    const float* __restrict__ Wa1, const float* __restrict__ ba1,
    const float* __restrict__ Wa2, const float* __restrict__ ba2,
    const float* __restrict__ Wih, const float* __restrict__ Whh,
    const float* __restrict__ bih, const float* __restrict__ bhh,
    const float* __restrict__ Wfc, const float* __restrict__ bfc,
    const float* __restrict__ Wfin, const float* __restrict__ bfin,
    float* __restrict__ out,
    uint32_t* __restrict__ ctrs,          // 3072 private flag lines (384 KB)
    _Float16* __restrict__ Ab,            // [128][1024] (d|c) f16 — agent-only
    float* __restrict__ glin,             // [128][2048] f32 (+biases) — agent-only
    float* __restrict__ partS,            // [64 p][16 w][2 b][64 t] f32 — agent-only
    _Float16* __restrict__ hx,            // [8192][512] f16
    _Float16* __restrict__ Wa1a,          // [512][1024] f16
    _Float16* __restrict__ Whh16,         // [2048][512] f16
    float* __restrict__ XW)               // [128][64] f32: sum_m Wfc[m]*f16(Xe[b,t,m])
{
    cg::grid_group gg = cg::this_grid();
    const int bid = blockIdx.x;
    const int tid = threadIdx.x;
    const int wave = tid >> 6, lane = tid & 63;
    const int l15 = lane & 15, kq = lane >> 4;
    const int gt = bid * 512 + tid;

    __shared__ __align__(16) char arena[143888];

    // ===== sync #1: flush poison-dirty ws lines from all L2s =====
    gg.sync();

    // ===== prologue: NORMAL stores, 128B-line-owned per thread/block =====
    if (gt < 8192) {                       // Wa1a [512][1024] <- Wa1[:,0:1024)
        int row = gt >> 4, seg = gt & 15;
        const float* src = Wa1 + (size_t)row * 1536 + seg * 64;
        _Float16* dp = Wa1a + (size_t)row * 1024 + seg * 64;
#pragma unroll
        for (int i = 0; i < 8; ++i) *(v8h*)(dp + i * 8) = cvt8(src + i * 8);
    } else if (gt < 24576) {               // Whh16 [2048][512]
        int u = gt - 8192;
        int row = u >> 3, seg = u & 7;
        const float* src = Whh + (size_t)row * 512 + seg * 64;
        _Float16* dp = Whh16 + (size_t)row * 512 + seg * 64;
#pragma unroll
        for (int i = 0; i < 8; ++i) *(v8h*)(dp + i * 8) = cvt8(src + i * 8);
    } else if (gt < 26624) {               // Ab zero: 2048 lines x 16 u64
        uint64_t* p = (uint64_t*)Ab + (size_t)(gt - 24576) * 16;
#pragma unroll
        for (int i = 0; i < 16; ++i) p[i] = 0ull;
    } else if (gt < 124928) {              // flags zero: 98304 u32 (384 KB)
        ctrs[gt - 26624] = 0u;
    }
    // XW[b*64+t] = sum_m Wfc[m] * f16(Xe[b,t,m]) — 8192 rows, 16 threads each
    {
        const int row = gt >> 4, sub = gt & 15;
        const float* src = Xe + (size_t)row * 512 + sub * 32;
        float acc = 0.0f;
#pragma unroll
        for (int i = 0; i < 32; ++i)
            acc += Wfc[sub * 32 + i] * (float)(_Float16)src[i];
#pragma unroll
        for (int off = 1; off < 16; off <<= 1) acc += __shfl_xor(acc, off, 64);
        if (sub == 0) XW[row] = acc;
    }
    // hx = f16(Xe @ Wa1[:,1024:]^T + ba1) — all 256 blocks
    {
        const int wg = bid * 8 + wave;                 // 0..2047
        const int mt = wg >> 2;
        const int nq = wg & 3;
        const float* Abase = Xe + (size_t)(mt * 16 + l15) * 512 + kq * 8;
        v8h afr[16];
#pragma unroll
        for (int ks = 0; ks < 16; ++ks) afr[ks] = cvt8(Abase + ks * 32);
#pragma unroll
        for (int i = 0; i < 8; ++i) {
            const int nt = nq * 8 + i;
            const float* Bbase = Wa1 + (size_t)(nt * 16 + l15) * 1536 + 1024 + kq * 8;
            v4f acc = {};
#pragma unroll 4
            for (int ks = 0; ks < 16; ++ks)
                acc = __builtin_amdgcn_mfma_f32_16x16x32_f16(afr[ks], cvt8(Bbase + ks * 32), acc, 0, 0, 0);
            const float bav = ba1[nt * 16 + l15];
            _Float16* hrow = hx + (size_t)(mt * 16 + kq * 4) * 512 + nt * 16 + l15;
#pragma unroll
            for (int r = 0; r < 4; ++r) hrow[(size_t)r * 512] = (_Float16)(acc[r] + bav);
        }
    }
    // ===== sync #2: publish prologue; all L2s clean =====
    gg.sync();

    if (bid >= 128 && bid < 192) return;

    // =========================== main recurrence =============================
    if (bid < 128) {
        // ------------ worker: s-slice [32w,+32) + glin [128w,+128) ------------
        const int r = bid >> 4, w = bid & 15;
        const int g16 = r * 16;
        const uint32_t* fPbase = ctrs + (size_t)(r * 128 + w * 8) * 32;     // poll 8
        uint32_t* fWAbase = ctrs + FWA_OFF + (size_t)(r * 128 + w) * 32;    // stride 16*32
        uint32_t* fWBbase = ctrs + FWB_OFF + (size_t)(r * 128 + w) * 32;
        _Float16* hxL = (_Float16*)arena;               // 64 KB, [c][cmb][8] chunked
        float* red = (float*)(arena + 65536);           // 64 KB (s / glin reduce)
        float* s_tile = (float*)(arena + 131072);       // 2 KB
        float* w2l = (float*)(arena + 133120);          // 128 B

        for (int cmb = tid; cmb < 1024; cmb += 512) {
            const int b = cmb >> 6, tt = cmb & 63;
            const _Float16* src = hx + ((size_t)(g16 + b) * 64 + tt) * 512 + w * 32;
#pragma unroll
            for (int c = 0; c < 4; ++c)
                *(v8h*)(hxL + ((size_t)(c * 1024 + cmb) << 3)) = *(const v8h*)(src + c * 8);
        }
        if (tid < 32) w2l[tid] = Wa2[w * 32 + tid];
        __syncthreads();

        const uint64_t* abase = (const uint64_t*)Ab + (size_t)(g16 + l15) * 256 + kq * 2;
        v8h B0r[4], B1r[4];
#pragma unroll
        for (int k2 = 0; k2 < 4; ++k2) {
            const int kk = wave * 4 + k2;
            B0r[k2] = *(const v8h*)(Wa1a + (size_t)(w * 32 + l15) * 1024 + kk * 32 + kq * 8);
            B1r[k2] = *(const v8h*)(Wa1a + (size_t)(w * 32 + 16 + l15) * 1024 + kk * 32 + kq * 8);
        }
        v8h Bgr[8][2];
#pragma unroll
        for (int nt = 0; nt < 8; ++nt)
#pragma unroll
            for (int i = 0; i < 2; ++i)
                Bgr[nt][i] = *(const v8h*)(Whh16 + (size_t)(w * 128 + nt * 16 + l15) * 512
                                           + (wave * 2 + i) * 32 + kq * 8);
        float bbv[4];
#pragma unroll
        for (int j = 0; j < 4; ++j) {
            const int gcol = w * 128 + ((tid + j * 512) & 127);
            bbv[j] = bih[gcol] + bhh[gcol];
        }
        uint32_t* partOut = (uint32_t*)partS;

        for (int t = 0; t < 64; ++t) {
            if (t) wait_lines(fPbase, 8, (uint32_t)t);
            // ---- ALL Ab fragment loads upfront (one latency) ----
            uint64_t ls[8], lg[4];
#pragma unroll
            for (int k2 = 0; k2 < 4; ++k2) {
                ls[2 * k2]     = ald64(abase + (wave * 4 + k2) * 8);
                ls[2 * k2 + 1] = ald64(abase + (wave * 4 + k2) * 8 + 1);
            }
#pragma unroll
            for (int i = 0; i < 2; ++i) {
                lg[2 * i]     = ald64(abase + (wave * 2 + i) * 8);
                lg[2 * i + 1] = ald64(abase + (wave * 2 + i) * 8 + 1);
            }
            // ---- s-slice MFMA: wave owns ksegs [4w,+4), B in registers ----
            v4f a0 = {}, a1 = {};
#pragma unroll
            for (int k2 = 0; k2 < 4; ++k2) {
                const v8h af = mkv8(ls[2 * k2], ls[2 * k2 + 1]);
                a0 = __builtin_amdgcn_mfma_f32_16x16x32_f16(af, B0r[k2], a0, 0, 0, 0);
                a1 = __builtin_amdgcn_mfma_f32_16x16x32_f16(af, B1r[k2], a1, 0, 0, 0);
            }
            // swizzled store: bank = (e + 2*row) & 31 -> <=2-way (free)
#pragma unroll
            for (int rr = 0; rr < 4; ++rr) {
                const int brow = kq * 4 + rr;
                red[wave * 512 + brow * 32 + ((l15 + 2 * brow) & 31)] = a0[rr];
                red[wave * 512 + brow * 32 + ((16 + l15 + 2 * brow) & 31)] = a1[rr];
            }
            __syncthreads();
            {
                const int brow2 = tid >> 5, e2 = tid & 31;
                const int sidx = brow2 * 32 + ((e2 + 2 * brow2) & 31);
                float ssum = 0.0f;
#pragma unroll
                for (int wv = 0; wv < 8; ++wv) ssum += red[wv * 512 + sidx];
                s_tile[tid] = ssum;
            }
            __syncthreads();

            // ---- tanh score partials: 2 (b,t) combos/thread ----
#pragma unroll
            for (int cc = 0; cc < 2; ++cc) {
                const int cmb = tid + cc * 512;
                const int b = cmb >> 6, tt = cmb & 63;
                const _Float16* hb = hxL + ((size_t)cmb << 3);
                float acc = 0.0f;
#pragma unroll
                for (int q = 0; q < 4; ++q) {
                    const v8h hv = *(const v8h*)(hb + ((size_t)q << 13));
#pragma unroll
                    for (int j = 0; j < 8; ++j)
                        acc += w2l[q * 8 + j] *
                               fast_tanh(s_tile[b * 32 + q * 8 + j] + (float)hv[j]);
                }
                const int pg = r * 8 + (b >> 1);
                ast32(partOut + (((size_t)pg * 16 + w) * 2 + (b & 1)) * 64 + tt,
                      __builtin_bit_cast(uint32_t, acc));
            }
            publish_lines(fWAbase, 8, 16 * 32, (uint32_t)(t + 1));

            // ---- glin (softmax shadow): wave owns d-ksegs [2w,+2), B in regs ----
#pragma unroll
            for (int nt = 0; nt < 8; ++nt) {
                v4f ag = {};
#pragma unroll
                for (int i = 0; i < 2; ++i)
                    ag = __builtin_amdgcn_mfma_f32_16x16x32_f16(
                        mkv8(lg[2 * i], lg[2 * i + 1]), Bgr[nt][i], ag, 0, 0, 0);
#pragma unroll
                for (int rr = 0; rr < 4; ++rr) {
                    const int row = kq * 4 + rr;
                    red[wave * 2048 + row * 128 + ((nt * 16 + l15 + 2 * row) & 127)] = ag[rr];
                }
            }
            __syncthreads();
#pragma unroll
            for (int j = 0; j < 4; ++j) {
                const int o = tid + j * 512;           // row*128+col
                const int row2 = o >> 7, col2 = o & 127;
                const int gidx = row2 * 128 + ((col2 + 2 * row2) & 127);
                float gsum = 0.0f;
#pragma unroll
                for (int wv = 0; wv < 8; ++wv) gsum += red[wv * 2048 + gidx];
                ast32((uint32_t*)glin + (size_t)(g16 + row2) * 2048 + w * 128 + col2,
                      __builtin_bit_cast(uint32_t, gsum + bbv[j]));
            }
            publish_lines(fWBbase, 8, 16 * 32, (uint32_t)(t + 1));
        }
    } else {
        // ------------------ pair block ------------------
        const int p = bid - 192, b0 = 2 * p, r = p >> 3, pl = p & 7;
        uint32_t* fPbase = ctrs + (size_t)(r * 128 + pl) * 32;              // stride 8*32, n=16
        const uint32_t* fWAbase = ctrs + FWA_OFF + (size_t)(r * 128 + pl * 16) * 32;  // poll 16
        const uint32_t* fWBbase = ctrs + FWB_OFF + (size_t)(r * 128 + pl * 16) * 32;  // poll 16
        _Float16* XeL = (_Float16*)arena;               // 128 KB
        float* sc = (float*)(arena + 131072);
        float* dstL = (float*)(arena + 131584);         // [2][512] (t=63 only)
        float* ctxl = (float*)(arena + 135680);         // [2][512] (t=63 only)
        float* ytl = (float*)(arena + 139776);
        float* red0 = (float*)(arena + 139784);
        float* XWl = (float*)(arena + 139792);          // 512 B

        {
            const float* xsrc = Xe + (size_t)b0 * 64 * 512;
#pragma unroll
            for (int i = 0; i < 16; ++i) {
                const int u = tid + i * 512;
                *(v8h*)(XeL + (size_t)u * 8) = cvt8(xsrc + (size_t)u * 8);
            }
        }
        if (tid < 128) XWl[tid] = XW[(size_t)(b0 + (tid >> 6)) * 64 + (tid & 63)];
        const float wih_i = Wih[tid], wih_f = Wih[512 + tid],
                    wih_g = Wih[1024 + tid], wih_o = Wih[1536 + tid];
        float creg[2] = {0.0f, 0.0f}, dreg[2] = {0.0f, 0.0f};
        uint32_t* Abu = (uint32_t*)Ab;
        const uint32_t* partB = (const uint32_t*)partS;
        __syncthreads();

        for (int t = 0; t < 64; ++t) {
            wait_lines(fWAbase, 16, (uint32_t)(t + 1));
            {   // sum 16 worker partials per (b,t): 4 threads per combo
                const int cmb = tid >> 2, wq = tid & 3;
                const int blv = cmb >> 6, tt = cmb & 63;
                float acc = 0.0f;
#pragma unroll
                for (int i = 0; i < 4; ++i)
                    acc += __builtin_bit_cast(float,
                        ald32(partB + (((size_t)p * 16 + wq * 4 + i) * 2 + blv) * 64 + tt));
                acc += __shfl_xor(acc, 1, 64);
                acc += __shfl_xor(acc, 2, 64);
                if (wq == 0) sc[cmb] = acc;
            }
            __syncthreads();

            // ---- joint softmax over the pair's 128 scores ----
            if (tid < 64) {
                float m2 = fmaxf(sc[tid], sc[tid + 64]);
#pragma unroll
                for (int off = 32; off; off >>= 1) m2 = fmaxf(m2, __shfl_xor(m2, off, 64));
                float e0v = __expf(sc[tid] - m2);
                float e1v = __expf(sc[tid + 64] - m2);
                sc[tid] = e0v; sc[tid + 64] = e1v;
                float ssum = e0v + e1v;
#pragma unroll
                for (int off = 32; off; off >>= 1) ssum += __shfl_xor(ssum, off, 64);
                if (tid == 0) red0[0] = 1.0f / ssum;
            }
            __syncthreads();
            const float inv = red0[0];

            // ---- glin ready; issue gate loads, drain under ytilde ----
            wait_lines(fWBbase, 16, (uint32_t)(t + 1));
            uint32_t gv[2][4];
#pragma unroll
            for (int blv = 0; blv < 2; ++blv) {
                const uint32_t* gb2 = (const uint32_t*)glin + (size_t)(b0 + blv) * 2048 + tid;
                gv[blv][0] = ald32(gb2);
                gv[blv][1] = ald32(gb2 + 512);
                gv[blv][2] = ald32(gb2 + 1024);
                gv[blv][3] = ald32(gb2 + 1536);
            }

            // ---- y_tilde via precomputed XW (context removed from loop) ----
            if (tid < 128) {
                const int blv = tid >> 6, l2 = tid & 63;
                float v = sc[blv * 64 + l2] * XWl[blv * 64 + l2];
#pragma unroll
                for (int off = 32; off; off >>= 1) v += __shfl_xor(v, off, 64);
                if (l2 == 0)
                    ytl[blv] = inv * v + Wfc[512] * ypr[(size_t)(b0 + blv) * 64 + t] + bfc[0];
            }
            __syncthreads();

            // ---- gates + LSTM update (reg state) + Ab publish ----
#pragma unroll
            for (int blv = 0; blv < 2; ++blv) {
                const float yt = ytl[blv];
                float ii = __builtin_bit_cast(float, gv[blv][0]) + yt * wih_i;
                float ff = __builtin_bit_cast(float, gv[blv][1]) + yt * wih_f;
                float ggv = __builtin_bit_cast(float, gv[blv][2]) + yt * wih_g;
                float oo = __builtin_bit_cast(float, gv[blv][3]) + yt * wih_o;
                float cn = fast_sigmoid(ff) * creg[blv] + fast_sigmoid(ii) * fast_tanh(ggv);
                float dn = fast_sigmoid(oo) * fast_tanh(cn);
                creg[blv] = cn;
                dreg[blv] = dn;
                float dp = __shfl_xor(dn, 1, 64);
                float cp = __shfl_xor(cn, 1, 64);
                if (!(tid & 1)) {
                    ast32(Abu + (size_t)(b0 + blv) * 512 + (tid >> 1), packh(dn, dp));
                    ast32(Abu + (size_t)(b0 + blv) * 512 + 256 + (tid >> 1), packh(cn, cp));
                }
            }
            publish_lines(fPbase, 16, 8 * 32, (uint32_t)(t + 1));

            if (t == 63) {
                // ---- context (only needed for the final output) ----
                {
                    const int blv = tid >> 8, m2 = (tid & 255) * 2;
                    const _Float16* xb = XeL + (size_t)blv * 64 * 512 + m2;
                    float a0 = 0.0f, a1 = 0.0f;
#pragma unroll 8
                    for (int tt = 0; tt < 64; ++tt) {
                        const h2v xv = *(const h2v*)(xb + (size_t)tt * 512);
                        const float bta = sc[blv * 64 + tt];
                        a0 += bta * (float)xv[0];
                        a1 += bta * (float)xv[1];
                    }
                    ctxl[blv * 512 + m2] = a0 * inv;
                    ctxl[blv * 512 + m2 + 1] = a1 * inv;
                }
                dstL[tid] = dreg[0];
                dstL[512 + tid] = dreg[1];
                __syncthreads();
                if (tid < 128) {
                    const int blv = tid >> 6, l2 = tid & 63;
                    float acc2 = 0.0f;
#pragma unroll
                    for (int j = 0; j < 8; ++j) {
                        const int e = l2 * 8 + j;
                        acc2 += dstL[blv * 512 + e] * Wfin[e] + ctxl[blv * 512 + e] * Wfin[512 + e];
                    }
#pragma unroll
                    for (int off = 32; off; off >>= 1) acc2 += __shfl_xor(acc2, off, 64);
                    if (l2 == 0) out[b0 + blv] = acc2 + bfin[0];
                }
            }
        }
    }
}

extern "C" void kernel_launch(void* const* d_in, const int* in_sizes, int n_in,
                              void* d_out, int out_size, void* d_ws, size_t ws_size,
                              hipStream_t stream)
{
    const float* Xe   = (const float*)d_in[0];
    const float* ypr  = (const float*)d_in[1];
    const float* Wa1  = (const float*)d_in[2];
    const float* ba1  = (const float*)d_in[3];
    const float* Wa2  = (const float*)d_in[4];
    const float* ba2  = (const float*)d_in[5];
    const float* Wih  = (const float*)d_in[6];
    const float* Whh  = (const float*)d_in[7];
    const float* bih  = (const float*)d_in[8];
    const float* bhh  = (const float*)d_in[9];
    const float* Wfc  = (const float*)d_in[10];
    const float* bfc  = (const float*)d_in[11];
    const float* Wfin = (const float*)d_in[12];
    const float* bfin = (const float*)d_in[13];
    float* out = (float*)d_out;

    char* w = (char*)d_ws;
    uint32_t* ctrs  = (uint32_t*)w;                 w += 393216;                       // 384 KB
    _Float16* Ab    = (_Float16*)w;                 w += (size_t)128 * 1024 * 2;       // 256 KB
    float*    glin  = (float*)w;                    w += (size_t)128 * 2048 * 4;       // 1 MB
    float*    partS = (float*)w;                    w += (size_t)64 * 16 * 2 * 64 * 4; // 512 KB
    _Float16* hx    = (_Float16*)w;                 w += (size_t)8192 * 512 * 2;       // 8 MB
    _Float16* Wa1a  = (_Float16*)w;                 w += (size_t)512 * 1024 * 2;       // 1 MB
    _Float16* Whh16 = (_Float16*)w;                 w += (size_t)2048 * 512 * 2;       // 2 MB
    float*    XW    = (float*)w;                    w += (size_t)128 * 64 * 4;         // 32 KB

    void* args[] = {
        (void*)&Xe, (void*)&ypr, (void*)&Wa1, (void*)&ba1, (void*)&Wa2, (void*)&ba2,
        (void*)&Wih, (void*)&Whh, (void*)&bih, (void*)&bhh, (void*)&Wfc, (void*)&bfc,
        (void*)&Wfin, (void*)&bfin, (void*)&out,
        (void*)&ctrs, (void*)&Ab, (void*)&glin, (void*)&partS, (void*)&hx,
        (void*)&Wa1a, (void*)&Whh16, (void*)&XW
    };
    hipLaunchCooperativeKernel((const void*)fused_decoder, dim3(256), dim3(512),
                               args, 0, stream);
}